// Round 2
// baseline (721.852 us; speedup 1.0000x reference)
//
#include <hip/hip_runtime.h>
#include <hip/hip_fp16.h>

#define NB 8          // batch
#define NS 4096       // seq len
#define NH 2048       // hidden
#define NDH 64        // selector hidden dim
#define NK 256        // top-k
#define BK 32         // gemm k-chunk per LDS stage
#define MT 128        // tokens per block
#define KS 4          // split-K factor
#define KCH (NH / KS) // 512 k per block

// ---------------------------------------------------------------------------
// K1: partial = hs @ w1 over this block's k-chunk, fused with fp16-rounded
// copy of hs into out0. Grid = 256 token-tiles x KS k-chunks = 1024 blocks,
// 256 threads (4 waves) -> 16 waves/CU. Thread tile 4 tok x 8 dh.
// Copy-out stores are issued at compute-phase start (drain under the FMA
// phase instead of serializing on the pre-barrier vmcnt(0) drain), and the
// next A/W tiles are register-prefetched during compute.
// ---------------------------------------------------------------------------
__global__ __launch_bounds__(256, 4) void k_sel_gemm(
    const float* __restrict__ hs, const float* __restrict__ w1,
    float* __restrict__ out0, float* __restrict__ part)
{
    __shared__ float As[MT][BK + 4];   // 36 floats/row, conflict-free (verified 0)
    __shared__ float Ws[BK][NDH];

    const int tid = threadIdx.x;
    const int tx = tid & 7;            // dh octet: dh = tx*8 .. tx*8+7
    const int ty = tid >> 3;           // 0..31: staging row + compute token group
    const int tile = blockIdx.x & 255;
    const int kc = blockIdx.x >> 8;
    const int tokenBase = tile * MT;
    const int kBase = kc * KCH;

    const int sK = (tid & 7) * 4;      // staging k-offset (floats)
    const long long aBase = (long long)(tokenBase + ty) * NH + kBase + sK;
    const int wRow = tid >> 4;         // 0..15
    const int wCol = (tid & 15) * 4;
    const float* wBase = w1 + (long long)(kBase + wRow) * NDH + wCol;

    float acc[4][8];
#pragma unroll
    for (int t = 0; t < 4; ++t)
#pragma unroll
        for (int j = 0; j < 8; ++j) acc[t][j] = 0.0f;

    // prologue: load first A/W tiles into registers
    float4 va[4], wv[2];
#pragma unroll
    for (int r = 0; r < 4; ++r)
        va[r] = *reinterpret_cast<const float4*>(hs + aBase + (long long)r * 32 * NH);
#pragma unroll
    for (int r = 0; r < 2; ++r)
        wv[r] = *reinterpret_cast<const float4*>(wBase + (long long)(r * 16) * NDH);

    for (int ko = 0; ko < KCH; ko += BK) {
        // ---- registers -> LDS
#pragma unroll
        for (int r = 0; r < 4; ++r)
            *reinterpret_cast<float4*>(&As[ty + r * 32][sK]) = va[r];
#pragma unroll
        for (int r = 0; r < 2; ++r)
            *reinterpret_cast<float4*>(&Ws[wRow + r * 16][wCol]) = wv[r];
        __syncthreads();

        // ---- deferred fp16-rounded copy-out: issued at compute-phase start,
        // store latency drains under ~1024 FMAs before the next barrier.
#pragma unroll
        for (int r = 0; r < 4; ++r) {
            float4 o;
            o.x = __half2float(__float2half(va[r].x));
            o.y = __half2float(__float2half(va[r].y));
            o.z = __half2float(__float2half(va[r].z));
            o.w = __half2float(__float2half(va[r].w));
            *reinterpret_cast<float4*>(out0 + aBase + ko + (long long)r * 32 * NH) = o;
        }
        // ---- register prefetch of next tiles (overlaps FMAs)
        if (ko + BK < KCH) {
#pragma unroll
            for (int r = 0; r < 4; ++r)
                va[r] = *reinterpret_cast<const float4*>(
                    hs + aBase + (ko + BK) + (long long)r * 32 * NH);
#pragma unroll
            for (int r = 0; r < 2; ++r)
                wv[r] = *reinterpret_cast<const float4*>(
                    wBase + (long long)(ko + BK + r * 16) * NDH);
        }

        // ---- FMA phase (identical k-accumulation order to verified kernel)
#pragma unroll
        for (int kk = 0; kk < BK; kk += 4) {
            float4 av[4];
#pragma unroll
            for (int t = 0; t < 4; ++t)
                av[t] = *reinterpret_cast<const float4*>(&As[ty + 32 * t][kk]);
#pragma unroll
            for (int i = 0; i < 4; ++i) {
                const float4 w0 = *reinterpret_cast<const float4*>(&Ws[kk + i][tx * 8]);
                const float4 w1v = *reinterpret_cast<const float4*>(&Ws[kk + i][tx * 8 + 4]);
#pragma unroll
                for (int t = 0; t < 4; ++t) {
                    const float a = reinterpret_cast<const float*>(&av[t])[i];
                    acc[t][0] += a * w0.x;  acc[t][1] += a * w0.y;
                    acc[t][2] += a * w0.z;  acc[t][3] += a * w0.w;
                    acc[t][4] += a * w1v.x; acc[t][5] += a * w1v.y;
                    acc[t][6] += a * w1v.z; acc[t][7] += a * w1v.w;
                }
            }
        }
        __syncthreads();
    }

    // ---- write partial sums: part[kc][token][dh]
#pragma unroll
    for (int t = 0; t < 4; ++t) {
        const long long o =
            ((long long)kc * (NB * NS) + tokenBase + ty + 32 * t) * NDH + tx * 8;
        *reinterpret_cast<float4*>(part + o) =
            make_float4(acc[t][0], acc[t][1], acc[t][2], acc[t][3]);
        *reinterpret_cast<float4*>(part + o + 4) =
            make_float4(acc[t][4], acc[t][5], acc[t][6], acc[t][7]);
    }
}

// ---------------------------------------------------------------------------
// K1b: logits[T] = relu(sum_kc part + b1) . w2 + b2. One wave per token.
// ---------------------------------------------------------------------------
__global__ __launch_bounds__(256) void k_reduce(
    const float* __restrict__ part, const float* __restrict__ b1,
    const float* __restrict__ w2, const float* __restrict__ b2,
    float* __restrict__ logits)
{
    const int T = blockIdx.x * 4 + (threadIdx.x >> 6);
    const int lane = threadIdx.x & 63;
    float s = 0.0f;
#pragma unroll
    for (int kc = 0; kc < KS; ++kc)
        s += part[((long long)kc * (NB * NS) + T) * NDH + lane];
    const float h = fmaxf(s + b1[lane], 0.0f);
    float p = h * w2[lane];
#pragma unroll
    for (int m = 1; m < 64; m <<= 1) p += __shfl_xor(p, m, 64);
    if (lane == 0) logits[T] = p + b2[0];
}

// ---------------------------------------------------------------------------
// K2: per-batch gumbel top-k via exact 32-bit radix select + O(C^2) ranking
// (comparator: key desc, index asc — matches jax.lax.top_k), plus
// log_softmax gather mean. One block per batch, 256 threads, with
// wave0-shuffle suffix-scan/threshold-select (3 barriers/pass vs ~20)
// and wave-shuffle reductions (2 barriers vs 10) — identical selection math.
// ---------------------------------------------------------------------------
__global__ __launch_bounds__(256) void k_topk(
    const float* __restrict__ logits, const float* __restrict__ noise,
    float* __restrict__ outIdx, float* __restrict__ outType,
    float* __restrict__ outLP, int* __restrict__ wsIdx)
{
    __shared__ unsigned int ukey[NS];
    __shared__ float rawl[NS];
    __shared__ unsigned int hist[256];
    __shared__ unsigned int candU[512];
    __shared__ int candIdx[512];
    __shared__ int sel[NK];
    __shared__ float redw[4];
    __shared__ unsigned int misc[3];   // 0: prefix, 1: rem, 2: candCount

    const int b = blockIdx.x;
    const int tid = threadIdx.x;
    const int lane = tid & 63;
    const int wid = tid >> 6;

    for (int e = tid; e < NS; e += 256) {
        const float l = logits[b * NS + e];
        const float u = noise[b * NS + e];
        const float g = -logf(-logf(u));
        unsigned int x = __float_as_uint(l + g);
        x = (x & 0x80000000u) ? ~x : (x | 0x80000000u);   // monotonic uint map
        ukey[e] = x;
        rawl[e] = l;
    }
    if (tid == 0) { misc[0] = 0u; misc[1] = NK; misc[2] = 0u; }
    __syncthreads();

    // exact radix select: after 4 passes misc[0] = T (32-bit threshold key)
    for (int pass = 0; pass < 4; ++pass) {
        const int shift = 24 - pass * 8;
        hist[tid] = 0u;
        __syncthreads();
        const unsigned int pfx = misc[0];
        const unsigned int rem = misc[1];
        for (int e = tid; e < NS; e += 256) {
            const unsigned int x = ukey[e];
            if (pass == 0 || (x >> (shift + 8)) == pfx)
                atomicAdd(&hist[(x >> shift) & 255u], 1u);
        }
        __syncthreads();
        if (tid < 64) {
            // lane l owns bins 4l..4l+3; suffix-sum entirely in-wave
            const unsigned int h0 = hist[4 * tid];
            const unsigned int h1 = hist[4 * tid + 1];
            const unsigned int h2 = hist[4 * tid + 2];
            const unsigned int h3 = hist[4 * tid + 3];
            const unsigned int g = h0 + h1 + h2 + h3;
            unsigned int s = g;
#pragma unroll
            for (int m = 1; m < 64; m <<= 1) {
                const unsigned int v = __shfl_down(s, m, 64);
                if (tid + m < 64) s += v;
            }
            const unsigned int Snext = s - g;   // sum over lanes > l
            const unsigned int s3 = Snext + h3;
            const unsigned int s2 = s3 + h2;
            const unsigned int s1 = s2 + h1;
            const unsigned int s0 = s1 + h0;
            const unsigned int ge[4] = { s0, s1, s2, s3 };
            const unsigned int gt[4] = { s1, s2, s3, Snext };
#pragma unroll
            for (int i = 0; i < 4; ++i) {
                if (ge[i] >= rem && gt[i] < rem) {       // unique bin
                    misc[0] = (pfx << 8) | (unsigned int)(4 * tid + i);
                    misc[1] = rem - gt[i];
                }
            }
        }
        __syncthreads();
    }

    const unsigned int T = misc[0];
    for (int e = tid; e < NS; e += 256) {
        if (ukey[e] >= T) {
            const unsigned int slot = atomicAdd(&misc[2], 1u);
            if (slot < 512u) { candU[slot] = ukey[e]; candIdx[slot] = e; }
        }
    }
    __syncthreads();
    const int C = (int)min(misc[2], 512u);

    // exact rank per candidate (C ~ 256): rank < NK -> emit at slot rank
    for (int c = tid; c < C; c += 256) {
        const unsigned int xu = candU[c];
        const int xi = candIdx[c];
        int r = 0;
        for (int j = 0; j < C; ++j) {
            const unsigned int yu = candU[j];
            r += (int)((yu > xu) || (yu == xu && candIdx[j] < xi));
        }
        if (r < NK) {
            outIdx[b * NK + r] = (float)xi;
            outType[b * NK + r] = 1.0f;   // FIXED_TYPE
            wsIdx[b * NK + r] = xi;
            sel[r] = xi;
        }
    }

    // log-softmax denominator over raw logits (wave-shuffle reductions)
    float lm = -INFINITY;
    for (int e = tid; e < NS; e += 256) lm = fmaxf(lm, rawl[e]);
#pragma unroll
    for (int m = 32; m; m >>= 1) lm = fmaxf(lm, __shfl_xor(lm, m, 64));
    if (lane == 0) redw[wid] = lm;
    __syncthreads();                     // also makes sel[] visible
    const float maxv = fmaxf(fmaxf(redw[0], redw[1]), fmaxf(redw[2], redw[3]));
    __syncthreads();
    float ls = 0.0f;
    for (int e = tid; e < NS; e += 256) ls += expf(rawl[e] - maxv);
#pragma unroll
    for (int m = 32; m; m >>= 1) ls += __shfl_xor(ls, m, 64);
    if (lane == 0) redw[wid] = ls;
    __syncthreads();
    const float lse = logf(redw[0] + redw[1] + redw[2] + redw[3]);
    __syncthreads();
    float contrib = rawl[sel[tid]] - maxv - lse;   // tid < NK == 256 always
#pragma unroll
    for (int m = 32; m; m >>= 1) contrib += __shfl_xor(contrib, m, 64);
    if (lane == 0) redw[wid] = contrib;
    __syncthreads();
    if (tid == 0) outLP[b] = (redw[0] + redw[1] + redw[2] + redw[3]) / (float)NK;
}

// ---------------------------------------------------------------------------
// K3: zero the selected rows of out0 (perturb value = TYPE_VALUES[1]*SCALE = 0)
// ---------------------------------------------------------------------------
__global__ __launch_bounds__(256) void k_zero_rows(
    const int* __restrict__ wsIdx, float* __restrict__ out0)
{
    const int blk = blockIdx.x;        // 0 .. NB*NK-1
    const int b = blk >> 8;
    const int r = blk & 255;
    const int row = wsIdx[b * NK + r];
    const float4 z = make_float4(0.f, 0.f, 0.f, 0.f);
    float4* p = reinterpret_cast<float4*>(out0 + ((long long)(b * NS + row)) * NH);
    p[threadIdx.x]       = z;
    p[threadIdx.x + 256] = z;
}

extern "C" void kernel_launch(void* const* d_in, const int* in_sizes, int n_in,
                              void* d_out, int out_size, void* d_ws, size_t ws_size,
                              hipStream_t stream) {
    const float* hs    = (const float*)d_in[0];   // (B,S,H) fp32
    const float* noise = (const float*)d_in[1];   // (B,S)   fp32
    const float* w1    = (const float*)d_in[2];   // (H,DH)
    const float* b1    = (const float*)d_in[3];   // (DH,)
    const float* w2    = (const float*)d_in[4];   // (DH,1)
    const float* b2    = (const float*)d_in[5];   // (1,)

    float* out0    = (float*)d_out;                       // (B,S,H) perturbed
    float* outIdx  = out0 + (long long)NB * NS * NH;      // (B,K) indices as float
    float* outType = outIdx + NB * NK;                    // (B,K) types as float
    float* outLP   = outType + NB * NK;                   // (B,)  log_prob

    float* logits = (float*)d_ws;                         // B*S floats
    int*   wsIdx  = (int*)d_ws + NB * NS;                 // B*K ints
    float* part   = (float*)d_ws + NB * NS + NB * NK;     // KS*B*S*DH floats (~33.5 MB)

    k_sel_gemm<<<256 * KS, 256, 0, stream>>>(hs, w1, out0, part);
    k_reduce<<<NB * NS / 4, 256, 0, stream>>>(part, b1, w2, b2, logits);
    k_topk<<<NB, 256, 0, stream>>>(logits, noise, outIdx, outType, outLP, wsIdx);
    k_zero_rows<<<NB * NK, 256, 0, stream>>>(wsIdx, out0);
}

// Round 3
// 512.945 us; speedup vs baseline: 1.4073x; 1.4073x over previous
//
#include <hip/hip_runtime.h>
#include <hip/hip_fp16.h>

#define NB 8          // batch
#define NS 4096       // seq len
#define NH 2048       // hidden
#define NDH 64        // selector hidden dim
#define NK 256        // top-k
#define BK 32         // gemm k-chunk per LDS stage
#define MT 128        // tokens per block
#define KS 4          // split-K factor
#define KCH (NH / KS) // 512 k per block

// ---------------------------------------------------------------------------
// K1: partial = hs @ w1 over this block's k-chunk, fused with fp16-rounded
// copy of hs into out0. Grid = 256 token-tiles x KS k-chunks = 1024 blocks,
// 256 threads (4 waves). Thread tile 4 tok x 8 dh.
// Copy-out stores issued at compute-phase start (drain under FMAs); next
// A/W tiles register-prefetched during compute.
// __launch_bounds__(256, 2): min 2 waves/EU -> VGPR cap 256. The (256,4)
// variant made a newer compiler clamp to 64 VGPRs and spill ~940 MB of
// scratch per dispatch (WRITE_SIZE 302->944 MB, dur 117->375 us). This
// kernel needs ~104 VGPRs; occupancy is LDS-limited regardless.
// ---------------------------------------------------------------------------
__global__ __launch_bounds__(256, 2) void k_sel_gemm(
    const float* __restrict__ hs, const float* __restrict__ w1,
    float* __restrict__ out0, float* __restrict__ part)
{
    __shared__ float As[MT][BK + 4];   // 36 floats/row, conflict-free
    __shared__ float Ws[BK][NDH];

    const int tid = threadIdx.x;
    const int tx = tid & 7;            // dh octet: dh = tx*8 .. tx*8+7
    const int ty = tid >> 3;           // 0..31: staging row + compute token group
    const int tile = blockIdx.x & 255;
    const int kc = blockIdx.x >> 8;
    const int tokenBase = tile * MT;
    const int kBase = kc * KCH;

    const int sK = (tid & 7) * 4;      // staging k-offset (floats)
    const long long aBase = (long long)(tokenBase + ty) * NH + kBase + sK;
    const int wRow = tid >> 4;         // 0..15
    const int wCol = (tid & 15) * 4;
    const float* wBase = w1 + (long long)(kBase + wRow) * NDH + wCol;

    float acc[4][8];
#pragma unroll
    for (int t = 0; t < 4; ++t)
#pragma unroll
        for (int j = 0; j < 8; ++j) acc[t][j] = 0.0f;

    // prologue: load first A/W tiles into registers
    float4 va[4], wv[2];
#pragma unroll
    for (int r = 0; r < 4; ++r)
        va[r] = *reinterpret_cast<const float4*>(hs + aBase + (long long)r * 32 * NH);
#pragma unroll
    for (int r = 0; r < 2; ++r)
        wv[r] = *reinterpret_cast<const float4*>(wBase + (long long)(r * 16) * NDH);

    for (int ko = 0; ko < KCH; ko += BK) {
        // ---- registers -> LDS
#pragma unroll
        for (int r = 0; r < 4; ++r)
            *reinterpret_cast<float4*>(&As[ty + r * 32][sK]) = va[r];
#pragma unroll
        for (int r = 0; r < 2; ++r)
            *reinterpret_cast<float4*>(&Ws[wRow + r * 16][wCol]) = wv[r];
        __syncthreads();

        // ---- deferred fp16-rounded copy-out: issued at compute-phase start,
        // store latency drains under ~1024 FMAs before the next barrier.
#pragma unroll
        for (int r = 0; r < 4; ++r) {
            float4 o;
            o.x = __half2float(__float2half(va[r].x));
            o.y = __half2float(__float2half(va[r].y));
            o.z = __half2float(__float2half(va[r].z));
            o.w = __half2float(__float2half(va[r].w));
            *reinterpret_cast<float4*>(out0 + aBase + ko + (long long)r * 32 * NH) = o;
        }
        // ---- register prefetch of next tiles (overlaps FMAs)
        if (ko + BK < KCH) {
#pragma unroll
            for (int r = 0; r < 4; ++r)
                va[r] = *reinterpret_cast<const float4*>(
                    hs + aBase + (ko + BK) + (long long)r * 32 * NH);
#pragma unroll
            for (int r = 0; r < 2; ++r)
                wv[r] = *reinterpret_cast<const float4*>(
                    wBase + (long long)(ko + BK + r * 16) * NDH);
        }

        // ---- FMA phase (identical k-accumulation order to verified kernel)
#pragma unroll
        for (int kk = 0; kk < BK; kk += 4) {
            float4 av[4];
#pragma unroll
            for (int t = 0; t < 4; ++t)
                av[t] = *reinterpret_cast<const float4*>(&As[ty + 32 * t][kk]);
#pragma unroll
            for (int i = 0; i < 4; ++i) {
                const float4 w0 = *reinterpret_cast<const float4*>(&Ws[kk + i][tx * 8]);
                const float4 w1v = *reinterpret_cast<const float4*>(&Ws[kk + i][tx * 8 + 4]);
#pragma unroll
                for (int t = 0; t < 4; ++t) {
                    const float a = reinterpret_cast<const float*>(&av[t])[i];
                    acc[t][0] += a * w0.x;  acc[t][1] += a * w0.y;
                    acc[t][2] += a * w0.z;  acc[t][3] += a * w0.w;
                    acc[t][4] += a * w1v.x; acc[t][5] += a * w1v.y;
                    acc[t][6] += a * w1v.z; acc[t][7] += a * w1v.w;
                }
            }
        }
        __syncthreads();
    }

    // ---- write partial sums: part[kc][token][dh]
#pragma unroll
    for (int t = 0; t < 4; ++t) {
        const long long o =
            ((long long)kc * (NB * NS) + tokenBase + ty + 32 * t) * NDH + tx * 8;
        *reinterpret_cast<float4*>(part + o) =
            make_float4(acc[t][0], acc[t][1], acc[t][2], acc[t][3]);
        *reinterpret_cast<float4*>(part + o + 4) =
            make_float4(acc[t][4], acc[t][5], acc[t][6], acc[t][7]);
    }
}

// ---------------------------------------------------------------------------
// K1b: logits[T] = relu(sum_kc part + b1) . w2 + b2. One wave per token.
// ---------------------------------------------------------------------------
__global__ __launch_bounds__(256) void k_reduce(
    const float* __restrict__ part, const float* __restrict__ b1,
    const float* __restrict__ w2, const float* __restrict__ b2,
    float* __restrict__ logits)
{
    const int T = blockIdx.x * 4 + (threadIdx.x >> 6);
    const int lane = threadIdx.x & 63;
    float s = 0.0f;
#pragma unroll
    for (int kc = 0; kc < KS; ++kc)
        s += part[((long long)kc * (NB * NS) + T) * NDH + lane];
    const float h = fmaxf(s + b1[lane], 0.0f);
    float p = h * w2[lane];
#pragma unroll
    for (int m = 1; m < 64; m <<= 1) p += __shfl_xor(p, m, 64);
    if (lane == 0) logits[T] = p + b2[0];
}

// ---------------------------------------------------------------------------
// K2: per-batch gumbel top-k via exact 32-bit radix select + O(C^2) ranking
// (comparator: key desc, index asc — matches jax.lax.top_k), plus
// log_softmax gather mean. One block per batch, 256 threads, with
// wave0-shuffle suffix-scan/threshold-select and wave-shuffle reductions.
// ---------------------------------------------------------------------------
__global__ __launch_bounds__(256) void k_topk(
    const float* __restrict__ logits, const float* __restrict__ noise,
    float* __restrict__ outIdx, float* __restrict__ outType,
    float* __restrict__ outLP, int* __restrict__ wsIdx)
{
    __shared__ unsigned int ukey[NS];
    __shared__ float rawl[NS];
    __shared__ unsigned int hist[256];
    __shared__ unsigned int candU[512];
    __shared__ int candIdx[512];
    __shared__ int sel[NK];
    __shared__ float redw[4];
    __shared__ unsigned int misc[3];   // 0: prefix, 1: rem, 2: candCount

    const int b = blockIdx.x;
    const int tid = threadIdx.x;
    const int lane = tid & 63;
    const int wid = tid >> 6;

    for (int e = tid; e < NS; e += 256) {
        const float l = logits[b * NS + e];
        const float u = noise[b * NS + e];
        const float g = -logf(-logf(u));
        unsigned int x = __float_as_uint(l + g);
        x = (x & 0x80000000u) ? ~x : (x | 0x80000000u);   // monotonic uint map
        ukey[e] = x;
        rawl[e] = l;
    }
    if (tid == 0) { misc[0] = 0u; misc[1] = NK; misc[2] = 0u; }
    __syncthreads();

    // exact radix select: after 4 passes misc[0] = T (32-bit threshold key)
    for (int pass = 0; pass < 4; ++pass) {
        const int shift = 24 - pass * 8;
        hist[tid] = 0u;
        __syncthreads();
        const unsigned int pfx = misc[0];
        const unsigned int rem = misc[1];
        for (int e = tid; e < NS; e += 256) {
            const unsigned int x = ukey[e];
            if (pass == 0 || (x >> (shift + 8)) == pfx)
                atomicAdd(&hist[(x >> shift) & 255u], 1u);
        }
        __syncthreads();
        if (tid < 64) {
            // lane l owns bins 4l..4l+3; suffix-sum entirely in-wave
            const unsigned int h0 = hist[4 * tid];
            const unsigned int h1 = hist[4 * tid + 1];
            const unsigned int h2 = hist[4 * tid + 2];
            const unsigned int h3 = hist[4 * tid + 3];
            const unsigned int g = h0 + h1 + h2 + h3;
            unsigned int s = g;
#pragma unroll
            for (int m = 1; m < 64; m <<= 1) {
                const unsigned int v = __shfl_down(s, m, 64);
                if (tid + m < 64) s += v;
            }
            const unsigned int Snext = s - g;   // sum over lanes > l
            const unsigned int s3 = Snext + h3;
            const unsigned int s2 = s3 + h2;
            const unsigned int s1 = s2 + h1;
            const unsigned int s0 = s1 + h0;
            const unsigned int ge[4] = { s0, s1, s2, s3 };
            const unsigned int gt[4] = { s1, s2, s3, Snext };
#pragma unroll
            for (int i = 0; i < 4; ++i) {
                if (ge[i] >= rem && gt[i] < rem) {       // unique bin
                    misc[0] = (pfx << 8) | (unsigned int)(4 * tid + i);
                    misc[1] = rem - gt[i];
                }
            }
        }
        __syncthreads();
    }

    const unsigned int T = misc[0];
    for (int e = tid; e < NS; e += 256) {
        if (ukey[e] >= T) {
            const unsigned int slot = atomicAdd(&misc[2], 1u);
            if (slot < 512u) { candU[slot] = ukey[e]; candIdx[slot] = e; }
        }
    }
    __syncthreads();
    const int C = (int)min(misc[2], 512u);

    // exact rank per candidate (C ~ 256): rank < NK -> emit at slot rank
    for (int c = tid; c < C; c += 256) {
        const unsigned int xu = candU[c];
        const int xi = candIdx[c];
        int r = 0;
        for (int j = 0; j < C; ++j) {
            const unsigned int yu = candU[j];
            r += (int)((yu > xu) || (yu == xu && candIdx[j] < xi));
        }
        if (r < NK) {
            outIdx[b * NK + r] = (float)xi;
            outType[b * NK + r] = 1.0f;   // FIXED_TYPE
            wsIdx[b * NK + r] = xi;
            sel[r] = xi;
        }
    }

    // log-softmax denominator over raw logits (wave-shuffle reductions)
    float lm = -INFINITY;
    for (int e = tid; e < NS; e += 256) lm = fmaxf(lm, rawl[e]);
#pragma unroll
    for (int m = 32; m; m >>= 1) lm = fmaxf(lm, __shfl_xor(lm, m, 64));
    if (lane == 0) redw[wid] = lm;
    __syncthreads();                     // also makes sel[] visible
    const float maxv = fmaxf(fmaxf(redw[0], redw[1]), fmaxf(redw[2], redw[3]));
    __syncthreads();
    float ls = 0.0f;
    for (int e = tid; e < NS; e += 256) ls += expf(rawl[e] - maxv);
#pragma unroll
    for (int m = 32; m; m >>= 1) ls += __shfl_xor(ls, m, 64);
    if (lane == 0) redw[wid] = ls;
    __syncthreads();
    const float lse = logf(redw[0] + redw[1] + redw[2] + redw[3]);
    __syncthreads();
    float contrib = rawl[sel[tid]] - maxv - lse;   // tid < NK == 256 always
#pragma unroll
    for (int m = 32; m; m >>= 1) contrib += __shfl_xor(contrib, m, 64);
    if (lane == 0) redw[wid] = contrib;
    __syncthreads();
    if (tid == 0) outLP[b] = (redw[0] + redw[1] + redw[2] + redw[3]) / (float)NK;
}

// ---------------------------------------------------------------------------
// K3: zero the selected rows of out0 (perturb value = TYPE_VALUES[1]*SCALE = 0)
// ---------------------------------------------------------------------------
__global__ __launch_bounds__(256) void k_zero_rows(
    const int* __restrict__ wsIdx, float* __restrict__ out0)
{
    const int blk = blockIdx.x;        // 0 .. NB*NK-1
    const int b = blk >> 8;
    const int r = blk & 255;
    const int row = wsIdx[b * NK + r];
    const float4 z = make_float4(0.f, 0.f, 0.f, 0.f);
    float4* p = reinterpret_cast<float4*>(out0 + ((long long)(b * NS + row)) * NH);
    p[threadIdx.x]       = z;
    p[threadIdx.x + 256] = z;
}

extern "C" void kernel_launch(void* const* d_in, const int* in_sizes, int n_in,
                              void* d_out, int out_size, void* d_ws, size_t ws_size,
                              hipStream_t stream) {
    const float* hs    = (const float*)d_in[0];   // (B,S,H) fp32
    const float* noise = (const float*)d_in[1];   // (B,S)   fp32
    const float* w1    = (const float*)d_in[2];   // (H,DH)
    const float* b1    = (const float*)d_in[3];   // (DH,)
    const float* w2    = (const float*)d_in[4];   // (DH,1)
    const float* b2    = (const float*)d_in[5];   // (1,)

    float* out0    = (float*)d_out;                       // (B,S,H) perturbed
    float* outIdx  = out0 + (long long)NB * NS * NH;      // (B,K) indices as float
    float* outType = outIdx + NB * NK;                    // (B,K) types as float
    float* outLP   = outType + NB * NK;                   // (B,)  log_prob

    float* logits = (float*)d_ws;                         // B*S floats
    int*   wsIdx  = (int*)d_ws + NB * NS;                 // B*K ints
    float* part   = (float*)d_ws + NB * NS + NB * NK;     // KS*B*S*DH floats (~33.5 MB)

    k_sel_gemm<<<256 * KS, 256, 0, stream>>>(hs, w1, out0, part);
    k_reduce<<<NB * NS / 4, 256, 0, stream>>>(part, b1, w2, b2, logits);
    k_topk<<<NB, 256, 0, stream>>>(logits, noise, outIdx, outType, outLP, wsIdx);
    k_zero_rows<<<NB * NK, 256, 0, stream>>>(wsIdx, out0);
}